// Round 2
// baseline (238.608 us; speedup 1.0000x reference)
//
#include <hip/hip_runtime.h>

#define CCH   256      // channels
#define HIDN  64       // hidden
#define NB    8        // batch
#define NHW   4096     // 64*64
#define GK    144      // groups * 9

// One fused kernel: block = 256 threads (4 waves) = one image row (64 px).
// lane = pixel (w). Wave w: hid channels [16w,16w+16), kmap j in [36w,36w+36)
// = groups [4w,4w+4) = output channels [64w,64w+64).
__global__ __launch_bounds__(256) void invol_fused(
    const float* __restrict__ x,        // [B,256,64,64]
    const float* __restrict__ w_reduce, // [64,256]
    const float* __restrict__ b_reduce, // [64]
    const float* __restrict__ w_span,   // [144,64]
    const float* __restrict__ b_span,   // [144]
    float* __restrict__ out)            // [B,256,64,64]
{
    __shared__ float smem[16384];                 // 64 KB: xs, later hid
    float (*xs)[64] = (float (*)[64])smem;        // [c][px]

    const int lane = threadIdx.x & 63;
    const int swid = __builtin_amdgcn_readfirstlane(threadIdx.x >> 6);

    const int row = blockIdx.x;                   // [0, 512)
    const int b   = row >> 6;
    const int hr  = row & 63;

    const float* xb = x + (size_t)b * (CCH * NHW) + hr * 64;  // row base

    // ---- stage: whole x row (256 ch x 64 px) -> LDS, 16B-wide async ----
    {
        const int cl = lane >> 4;                 // sub-channel 0..3
        const int p4 = (lane & 15) * 4;           // pixel*4
        #pragma unroll
        for (int t = 0; t < 16; ++t) {
            const int c0 = swid * 64 + t * 4;     // 4 channels per instr
            const float* src = xb + (size_t)(c0 + cl) * NHW + p4;
            __builtin_amdgcn_global_load_lds(
                (const __attribute__((address_space(1))) unsigned int*)src,
                (__attribute__((address_space(3))) unsigned int*)&xs[c0][0],
                16, 0, 0);
        }
    }
    __syncthreads();                              // drains vmcnt

    // ---- phase 1: hid slice (16 channels per wave), x from LDS ----
    const int o0 = swid * 16;
    float acc[16];
    #pragma unroll
    for (int i = 0; i < 16; ++i) acc[i] = b_reduce[o0 + i];

    #pragma unroll 4
    for (int c = 0; c < CCH; ++c) {
        const float xv = xs[c][lane];             // conflict-free ds_read
        #pragma unroll
        for (int i = 0; i < 16; ++i)
            acc[i] = fmaf(w_reduce[(o0 + i) * CCH + c], xv, acc[i]); // s_load
    }
    __syncthreads();                              // all waves done reading xs

    float (*hid)[65] = (float (*)[65])smem;       // union over dead xs
    #pragma unroll
    for (int i = 0; i < 16; ++i) hid[lane][o0 + i] = fmaxf(acc[i], 0.0f);
    __syncthreads();

    // ---- phase 2: kv[36] for this wave's 4 groups, fully in registers ----
    float h[64];
    #pragma unroll
    for (int o = 0; o < HIDN; ++o) h[o] = hid[lane][o];

    const bool vwm = (lane > 0), vwp = (lane < 63);
    const bool vhm = (hr  > 0), vhp = (hr  < 63);
    const bool vk[9] = { vhm && vwm, vhm, vhm && vwp,
                         vwm,        true, vwp,
                         vhp && vwm, vhp, vhp && vwp };

    float kv[36];
    #pragma unroll
    for (int jj = 0; jj < 36; ++jj) {             // j = 36*wid + jj, tap k = jj%9
        const int j = swid * 36 + jj;
        float a = b_span[j];
        #pragma unroll
        for (int o = 0; o < HIDN; ++o)
            a = fmaf(w_span[j * HIDN + o], h[o], a);   // s_load weights
        kv[jj] = vk[jj % 9] ? a : 0.0f;           // fold border mask into kv
    }

    // ---- phase 3: apply. 64 channels per wave, 9 taps each ----
    const int oWm = vwm ? -1  : 0, oWp = vwp ? 1  : 0;
    const int oHm = vhm ? -64 : 0, oHp = vhp ? 64 : 0;
    const int oo[9] = { oHm + oWm, oHm, oHm + oWp,
                        oWm,       0,   oWp,
                        oHp + oWm, oHp, oHp + oWp };

    const float* xrow = xb + lane;                      // + c*NHW per channel
    float*       orow = out + (size_t)b * (CCH * NHW) + hr * 64 + lane;

    #pragma unroll
    for (int gl = 0; gl < 4; ++gl) {                    // group within wave
        #pragma unroll 4
        for (int n = 0; n < 16; ++n) {                  // channel within group
            const int c = swid * 64 + gl * 16 + n;
            const float* xc = xrow + (size_t)c * NHW;
            float a = 0.0f;
            #pragma unroll
            for (int k = 0; k < 9; ++k)                 // static kv/oo indices
                a = fmaf(xc[oo[k]], kv[gl * 9 + k], a);
            orow[(size_t)c * NHW] = a;
        }
    }
}

// ---------------------------------------------------------------------------
extern "C" void kernel_launch(void* const* d_in, const int* in_sizes, int n_in,
                              void* d_out, int out_size, void* d_ws, size_t ws_size,
                              hipStream_t stream) {
    const float* x        = (const float*)d_in[0];
    const float* w_reduce = (const float*)d_in[1];
    const float* b_reduce = (const float*)d_in[2];
    const float* w_span   = (const float*)d_in[3];
    const float* b_span   = (const float*)d_in[4];
    float* out = (float*)d_out;

    invol_fused<<<dim3(NB * 64), dim3(256), 0, stream>>>(
        x, w_reduce, b_reduce, w_span, b_span, out);
}

// Round 5
// 125.987 us; speedup vs baseline: 1.8939x; 1.8939x over previous
//
#include <hip/hip_runtime.h>

#define CCH   256      // channels
#define HIDN  64       // hidden
#define GK    144      // groups * 9
#define NB    8        // batch
#define NHW   4096     // 64*64
#define NG    16
#define CPG   16

// ws layout (floats): w1T[256*64] | w2T[64*144] | kmap[8*144*4096]
#define W1T_OFF  0
#define W2T_OFF  16384
#define KMAP_OFF 25600           // 102400 B, 256B-aligned

// ---------------------------------------------------------------------------
// Kernel 0: transpose weights so gen's scalar loads are contiguous.
// w1T[c][o] = w_reduce[o][c]   (256x64)
// w2T[o][j] = w_span[j][o]     (64x144)
// ---------------------------------------------------------------------------
__global__ __launch_bounds__(256) void wtrans_kernel(
    const float* __restrict__ w_reduce, const float* __restrict__ w_span,
    float* __restrict__ ws)
{
    const int idx = blockIdx.x * 256 + threadIdx.x;   // 100 blocks * 256 = 25600
    if (idx < 16384) {
        const int c = idx >> 6, o = idx & 63;
        ws[W1T_OFF + idx] = w_reduce[o * CCH + c];
    } else {
        const int i2 = idx - 16384;                   // < 9216
        const int o = i2 / 144, j = i2 - o * 144;
        ws[W2T_OFF + i2] = w_span[j * HIDN + o];
    }
}

// ---------------------------------------------------------------------------
// Kernel 1: kernel generation. block = 512 threads (8 waves) = one image row.
// lane = pixel. wave w: hid channels [8w, 8w+8), then kmap j in [18w, 18w+18).
// All weight loads wave-uniform + contiguous -> s_load_dwordxN.
// ---------------------------------------------------------------------------
__global__ __launch_bounds__(512, 4) void gen_kernel(
    const float* __restrict__ x,        // [B,256,64,64]
    const float* __restrict__ b_reduce, // [64]
    const float* __restrict__ b_span,   // [144]
    const float* __restrict__ ws_ro,    // w1T / w2T
    float* __restrict__ kmap)           // [B,144,4096]
{
    __shared__ float smem[16384];                 // 64 KB
    float (*xs)[64] = (float (*)[64])smem;        // [c][px]

    const float* __restrict__ w1T = ws_ro + W1T_OFF;
    const float* __restrict__ w2T = ws_ro + W2T_OFF;

    const int lane = threadIdx.x & 63;
    const int wid  = __builtin_amdgcn_readfirstlane(threadIdx.x >> 6);

    const int row = blockIdx.x;                   // [0, 512)
    const int b   = row >> 6;
    const int hr  = row & 63;

    const float* xb = x + (size_t)b * (CCH * NHW) + hr * 64;

    // ---- stage whole row (256 ch x 64 px = 64 KB) via global_load_lds ----
    {
        const int cl = lane >> 4;                 // sub-channel 0..3
        const int p4 = (lane & 15) * 4;
        #pragma unroll
        for (int t = 0; t < 8; ++t) {
            const int c0 = wid * 32 + t * 4;      // 8 waves x 8 iters x 4 ch
            const float* src = xb + (size_t)(c0 + cl) * NHW + p4;
            __builtin_amdgcn_global_load_lds(
                (const __attribute__((address_space(1))) unsigned int*)src,
                (__attribute__((address_space(3))) unsigned int*)&xs[c0][0],
                16, 0, 0);
        }
    }
    __syncthreads();

    // ---- phase 1: 8 hid channels per wave ----
    const int o0 = wid * 8;
    float acc[8];
    #pragma unroll
    for (int i = 0; i < 8; ++i) acc[i] = b_reduce[o0 + i];

    #pragma unroll 8
    for (int c = 0; c < CCH; ++c) {
        const float xv = xs[c][lane];             // 1 ds_read per 8 FMA
        const float* w1c = w1T + c * HIDN + o0;   // uniform, contiguous
        #pragma unroll
        for (int i = 0; i < 8; ++i)
            acc[i] = fmaf(w1c[i], xv, acc[i]);
    }
    __syncthreads();                              // all waves done with xs

    float (*hid)[65] = (float (*)[65])smem;       // overlay dead xs
    #pragma unroll
    for (int i = 0; i < 8; ++i) hid[lane][o0 + i] = fmaxf(acc[i], 0.0f);
    __syncthreads();

    // ---- phase 2: 18 kmap channels (2 groups) per wave ----
    const int j0 = wid * 18;                      // j0 % 9 == 0
    float kv[18];
    #pragma unroll
    for (int jj = 0; jj < 18; ++jj) kv[jj] = b_span[j0 + jj];

    #pragma unroll 4
    for (int o = 0; o < HIDN; ++o) {
        const float hv = hid[lane][o];            // 1 ds_read per 18 FMA
        const float* w2o = w2T + o * GK + j0;     // uniform, contiguous
        #pragma unroll
        for (int jj = 0; jj < 18; ++jj)
            kv[jj] = fmaf(w2o[jj], hv, kv[jj]);
    }

    // ---- border mask folded into kmap values ----
    const bool vwm = (lane > 0), vwp = (lane < 63);
    const bool vhm = (hr  > 0), vhp = (hr  < 63);
    const bool vk[9] = { vhm && vwm, vhm, vhm && vwp,
                         vwm,        true, vwp,
                         vhp && vwm, vhp, vhp && vwp };

    float* kout = kmap + (size_t)b * (GK * NHW) + hr * 64 + lane;
    #pragma unroll
    for (int jj = 0; jj < 18; ++jj)               // tap k = jj % 9 (j0%9==0)
        kout[(size_t)(j0 + jj) * NHW] = vk[jj % 9] ? kv[jj] : 0.0f;
}

// ---------------------------------------------------------------------------
// Kernel 2: apply. thread = (b, g, hw); 16 channels of its group.
// kmap already border-masked; offsets clamped so reads stay in-bounds.
// ---------------------------------------------------------------------------
__global__ __launch_bounds__(256) void apply_kernel(
    const float* __restrict__ x,     // [B,256,64,64]
    const float* __restrict__ kmap,  // [B,144,4096]
    float* __restrict__ out)         // [B,256,64,64]
{
    const int t  = blockIdx.x * 256 + threadIdx.x;   // [0, B*G*HW)
    const int hw = t & 4095;
    const int bg = t >> 12;
    const int g  = bg & 15;
    const int b  = bg >> 4;
    const int h  = hw >> 6;
    const int w  = hw & 63;

    const float* kp = kmap + ((size_t)b * GK + g * 9) * NHW + hw;
    float kv[9];
    int   off[9];
    #pragma unroll
    for (int di = 0; di < 3; ++di) {
        const int hh  = h + di - 1;
        const int hcl = min(max(hh, 0), 63);
        #pragma unroll
        for (int dj = 0; dj < 3; ++dj) {
            const int ww  = w + dj - 1;
            const int wcl = min(max(ww, 0), 63);
            const int k   = di * 3 + dj;
            kv[k]  = kp[k * NHW];                 // masked already
            off[k] = (hcl - h) * 64 + (wcl - w);  // clamped (safe) tap
        }
    }

    const float* xp = x   + ((size_t)b * CCH + g * CPG) * NHW + hw;
    float*       op = out + ((size_t)b * CCH + g * CPG) * NHW + hw;

    #pragma unroll 4
    for (int n = 0; n < CPG; ++n) {
        float acc = 0.0f;
        #pragma unroll
        for (int k = 0; k < 9; ++k)
            acc = fmaf(xp[n * NHW + off[k]], kv[k], acc);
        op[n * NHW] = acc;
    }
}

// ---------------------------------------------------------------------------
extern "C" void kernel_launch(void* const* d_in, const int* in_sizes, int n_in,
                              void* d_out, int out_size, void* d_ws, size_t ws_size,
                              hipStream_t stream) {
    const float* x        = (const float*)d_in[0];
    const float* w_reduce = (const float*)d_in[1];
    const float* b_reduce = (const float*)d_in[2];
    const float* w_span   = (const float*)d_in[3];
    const float* b_span   = (const float*)d_in[4];
    float* out = (float*)d_out;
    float* ws  = (float*)d_ws;    // needs 102400 B + 18.87 MB

    float* kmap = ws + KMAP_OFF;

    wtrans_kernel<<<dim3(100), dim3(256), 0, stream>>>(w_reduce, w_span, ws);
    gen_kernel<<<dim3(NB * 64), dim3(512), 0, stream>>>(
        x, b_reduce, b_span, ws, kmap);
    apply_kernel<<<dim3(NB * NG * NHW / 256), dim3(256), 0, stream>>>(
        x, kmap, out);
}

// Round 6
// 121.440 us; speedup vs baseline: 1.9648x; 1.0374x over previous
//
#include <hip/hip_runtime.h>

#define CCH   256      // channels
#define HIDN  64       // hidden
#define GK    144      // groups * 9
#define NB    8        // batch
#define NHW   4096     // 64*64

// ws layout (floats): w1T[256*64] | w2T[64*144]
#define W1T_OFF  0
#define W2T_OFF  16384

// ---------------------------------------------------------------------------
// Kernel 0: transpose weights so fused kernel's scalar loads are contiguous.
// w1T[c][o] = w_reduce[o][c]   (256x64)
// w2T[o][j] = w_span[j][o]     (64x144)
// ---------------------------------------------------------------------------
__global__ __launch_bounds__(256) void wtrans_kernel(
    const float* __restrict__ w_reduce, const float* __restrict__ w_span,
    float* __restrict__ ws)
{
    const int idx = blockIdx.x * 256 + threadIdx.x;   // 100 blocks * 256 = 25600
    if (idx < 16384) {
        const int c = idx >> 6, o = idx & 63;
        ws[W1T_OFF + idx] = w_reduce[o * CCH + c];
    } else {
        const int i2 = idx - 16384;                   // < 9216
        const int o = i2 / 144, j = i2 - o * 144;
        ws[W2T_OFF + i2] = w_span[j * HIDN + o];
    }
}

// ---------------------------------------------------------------------------
// Fused involution: block = 512 threads (8 waves) = one image row (64 px).
// lane = pixel. Wave w:
//   phase 1: hid channels [8w, 8w+8)
//   phase 2: kmap j in [18w, 18w+18)  == groups {2w, 2w+1}   (registers only!)
//   apply  : output channels [32w, 32w+32) of its 2 groups
// XCD swizzle: block j -> row (j%8)*64 + j/8, so XCD i owns image i and all
// h+-1 neighbor-row reuse in apply hits the same XCD's L2.
// ---------------------------------------------------------------------------
__global__ __launch_bounds__(512, 4) void invol_fused(
    const float* __restrict__ x,        // [B,256,64,64]
    const float* __restrict__ b_reduce, // [64]
    const float* __restrict__ b_span,   // [144]
    const float* __restrict__ ws_ro,    // w1T / w2T
    float* __restrict__ out)            // [B,256,64,64]
{
    __shared__ float smem[16384];                 // 64 KB: xs, later hid
    float (*xs)[64] = (float (*)[64])smem;        // [c][px]

    const float* __restrict__ w1T = ws_ro + W1T_OFF;
    const float* __restrict__ w2T = ws_ro + W2T_OFF;

    const int lane = threadIdx.x & 63;
    const int wid  = __builtin_amdgcn_readfirstlane(threadIdx.x >> 6);

    const int raw = blockIdx.x;                   // [0, 512)
    const int row = ((raw & 7) << 6) | (raw >> 3);// bijective XCD chunk swizzle
    const int b   = row >> 6;
    const int hr  = row & 63;

    const float* xb = x + (size_t)b * (CCH * NHW) + hr * 64;

    // ---- stage whole row (256 ch x 64 px = 64 KB) via global_load_lds ----
    {
        const int cl = lane >> 4;                 // sub-channel 0..3
        const int p4 = (lane & 15) * 4;
        #pragma unroll
        for (int t = 0; t < 8; ++t) {
            const int c0 = wid * 32 + t * 4;      // 8 waves x 8 iters x 4 ch
            const float* src = xb + (size_t)(c0 + cl) * NHW + p4;
            __builtin_amdgcn_global_load_lds(
                (const __attribute__((address_space(1))) unsigned int*)src,
                (__attribute__((address_space(3))) unsigned int*)&xs[c0][0],
                16, 0, 0);
        }
    }
    __syncthreads();

    // ---- phase 1: 8 hid channels per wave ----
    const int o0 = wid * 8;
    float acc[8];
    #pragma unroll
    for (int i = 0; i < 8; ++i) acc[i] = b_reduce[o0 + i];

    #pragma unroll 8
    for (int c = 0; c < CCH; ++c) {
        const float xv = xs[c][lane];             // conflict-free ds_read
        const float* w1c = w1T + c * HIDN + o0;   // uniform, contiguous
        #pragma unroll
        for (int i = 0; i < 8; ++i)
            acc[i] = fmaf(w1c[i], xv, acc[i]);
    }
    __syncthreads();                              // all waves done reading xs

    // hid overlay: [o][px] layout -> conflict-free writes AND reads, no pad
    float (*hid)[64] = (float (*)[64])smem;
    #pragma unroll
    for (int i = 0; i < 8; ++i) hid[o0 + i][lane] = fmaxf(acc[i], 0.0f);
    __syncthreads();

    // ---- phase 2: kv[18] = kmap for this wave's 2 groups, registers only ----
    const int j0 = wid * 18;                      // j0 % 9 == 0
    float kv[18];
    #pragma unroll
    for (int jj = 0; jj < 18; ++jj) kv[jj] = b_span[j0 + jj];

    #pragma unroll 4
    for (int o = 0; o < HIDN; ++o) {
        const float hv = hid[o][lane];            // conflict-free ds_read
        const float* w2o = w2T + o * GK + j0;     // uniform, contiguous
        #pragma unroll
        for (int jj = 0; jj < 18; ++jj)
            kv[jj] = fmaf(w2o[jj], hv, kv[jj]);
    }

    // ---- fold border mask into kv ----
    const bool vwm = (lane > 0), vwp = (lane < 63);
    const bool vhm = (hr  > 0), vhp = (hr  < 63);
    const bool vk[9] = { vhm && vwm, vhm, vhm && vwp,
                         vwm,        true, vwp,
                         vhp && vwm, vhp, vhp && vwp };
    #pragma unroll
    for (int jj = 0; jj < 18; ++jj)
        kv[jj] = vk[jj % 9] ? kv[jj] : 0.0f;

    // ---- apply: 32 channels (2 groups) per wave, 9 taps each ----
    const int oWm = vwm ? -1  : 0, oWp = vwp ? 1  : 0;
    const int oHm = vhm ? -64 : 0, oHp = vhp ? 64 : 0;
    const int oo[9] = { oHm + oWm, oHm, oHm + oWp,
                        oWm,       0,   oWp,
                        oHp + oWm, oHp, oHp + oWp };

    const float* xrow = xb + lane;                // + c*NHW per channel
    float*       orow = out + (size_t)b * (CCH * NHW) + hr * 64 + lane;

    #pragma unroll 4
    for (int m = 0; m < 32; ++m) {                // channel within wave
        const int c  = wid * 32 + m;
        const int gl = m >> 4;                    // group-local 0/1
        const float* xc = xrow + (size_t)c * NHW;
        float a = 0.0f;
        #pragma unroll
        for (int k = 0; k < 9; ++k)               // static kv/oo indices
            a = fmaf(xc[oo[k]], kv[gl * 9 + k], a);
        orow[(size_t)c * NHW] = a;
    }
}

// ---------------------------------------------------------------------------
extern "C" void kernel_launch(void* const* d_in, const int* in_sizes, int n_in,
                              void* d_out, int out_size, void* d_ws, size_t ws_size,
                              hipStream_t stream) {
    const float* x        = (const float*)d_in[0];
    const float* w_reduce = (const float*)d_in[1];
    const float* b_reduce = (const float*)d_in[2];
    const float* w_span   = (const float*)d_in[3];
    const float* b_span   = (const float*)d_in[4];
    float* out = (float*)d_out;
    float* ws  = (float*)d_ws;    // needs 102400 B

    wtrans_kernel<<<dim3(100), dim3(256), 0, stream>>>(w_reduce, w_span, ws);
    invol_fused<<<dim3(NB * 64), dim3(512), 0, stream>>>(
        x, b_reduce, b_span, ws, out);
}